// Round 6
// baseline (327.673 us; speedup 1.0000x reference)
//
#include <hip/hip_runtime.h>

typedef __bf16 bf16;
typedef __bf16 bf16x8 __attribute__((ext_vector_type(8)));
typedef __bf16 bf16x4 __attribute__((ext_vector_type(4)));
typedef float f32x4 __attribute__((ext_vector_type(4)));
typedef float fx2 __attribute__((ext_vector_type(2)));
typedef unsigned int u32x2 __attribute__((ext_vector_type(2)));

#define DEV static __device__ __forceinline__

constexpr int BB = 2, SS = 2048, DM = 1024, NH = 16, HD = 64;
constexpr int MTOT = BB * SS;  // 4096
constexpr float LOG2E = 1.4426950408889634f;

// ---- workspace layout (bytes) ----
constexpr size_t OFF_XB   = 0;                                  // bf16 [4096][1024]
constexpr size_t OFF_WQKV = OFF_XB   + (size_t)MTOT * DM * 2;   // bf16 [3072][1024]
constexpr size_t OFF_WO   = OFF_WQKV + (size_t)3 * DM * DM * 2; // bf16 [1024][1024]
constexpr size_t OFF_TAB  = OFF_WO   + (size_t)DM * DM * 2;     // fx2  [2048][32]
constexpr size_t OFF_Q    = OFF_TAB  + (size_t)SS * (HD/2) * 8; // bf16 (B,H,S,d)
constexpr size_t OFF_K    = OFF_Q    + (size_t)MTOT * DM * 2;
constexpr size_t OFF_VT   = OFF_K    + (size_t)MTOT * DM * 2;   // bf16 (B,H,d,S)
constexpr size_t OFF_AO   = OFF_VT   + (size_t)MTOT * DM * 2;   // bf16 [4096][1024]

typedef const __attribute__((address_space(1))) void gas_void;
typedef __attribute__((address_space(3))) void las_void;

DEV void gload16(const bf16* g, bf16* l) {
  __builtin_amdgcn_global_load_lds((gas_void*)g, (las_void*)l, 16, 0, 0);
}

DEV f32x4 mfma16(bf16x8 a, bf16x8 b, f32x4 c) {
  return __builtin_amdgcn_mfma_f32_16x16x32_bf16(a, b, c, 0, 0, 0);
}

DEV unsigned pack2(float a, float b) {
  union { bf16 h[2]; unsigned u; } cv;
  cv.h[0] = (bf16)a; cv.h[1] = (bf16)b;
  return cv.u;
}

DEV u32x2 tr_read(unsigned addr) {
  u32x2 r;
  asm volatile("ds_read_b64_tr_b16 %0, %1" : "=v"(r) : "v"(addr));
  return r;
}

DEV bf16x8 combine4(u32x2 r0, u32x2 r1) {
  union { unsigned u[4]; bf16x8 v; } cv;
  cv.u[0] = r0[0]; cv.u[1] = r0[1]; cv.u[2] = r1[0]; cv.u[3] = r1[1];
  return cv.v;
}

// ---------------- prep: fp32 -> bf16 casts + RoPE table ----------------
__global__ void prep_kernel(const float* __restrict__ x, const float* __restrict__ wq,
    const float* __restrict__ wk, const float* __restrict__ wv, const float* __restrict__ wo,
    const int* __restrict__ pos, bf16* __restrict__ xb, bf16* __restrict__ wqkv,
    bf16* __restrict__ wob, fx2* __restrict__ tab) {
  const int NX4 = MTOT * DM / 4;     // 1048576
  const int NW4 = DM * DM / 4;       // 262144 = 2^18
  const int TOTC = NX4 + 4 * NW4;    // 2097152
  const int NTAB = SS * (HD / 2);    // 65536
  const int total = TOTC + NTAB;
  for (int i = blockIdx.x * blockDim.x + threadIdx.x; i < total; i += gridDim.x * blockDim.x) {
    if (i < TOTC) {
      const float* src; bf16* dst; int off;
      if (i < NX4) { src = x; dst = xb; off = i; }
      else {
        int i2 = i - NX4; int which = i2 >> 18; off = i2 & (NW4 - 1);
        src = which == 0 ? wq : which == 1 ? wk : which == 2 ? wv : wo;
        dst = which == 0 ? wqkv : which == 1 ? wqkv + DM * DM : which == 2 ? wqkv + 2 * DM * DM : wob;
      }
      float4 v = ((const float4*)src)[off];
      bf16x4 o4 = { (bf16)v.x, (bf16)v.y, (bf16)v.z, (bf16)v.w };
      ((bf16x4*)dst)[off] = o4;
    } else {
      int e = i - TOTC;
      int s = e >> 5, p = e & 31;
      float invf = __builtin_exp2f(-(float)p * (13.287712379549449f / 32.0f));
      float ang = (float)pos[s] * invf;
      fx2 cs; cs.x = cosf(ang); cs.y = sinf(ang);
      tab[e] = cs;
    }
  }
}

// ---------------- 128x128 bf16 GEMM mainloop (C[m,n] = sum_k A[m,k]*B[n,k]) ----------------
DEV void gemm_bt_128(const bf16* __restrict__ A, const bf16* __restrict__ Bw,
                     int rowA0, int rowB0, f32x4 (&acc)[4][4]) {
  __shared__ __align__(16) bf16 lA[128 * 32];
  __shared__ __align__(16) bf16 lB[128 * 32];
  const int t = threadIdx.x, w = t >> 6, lane = t & 63;
  const int wr = w >> 1, wc = w & 1, g = lane >> 4, c = lane & 15;
#pragma unroll
  for (int mi = 0; mi < 4; mi++)
#pragma unroll
    for (int ni = 0; ni < 4; ni++) acc[mi][ni] = (f32x4){0.f, 0.f, 0.f, 0.f};
  const bf16* ga = A + (size_t)(rowA0 + (t >> 2)) * DM + (t & 3) * 8;
  const bf16* gb = Bw + (size_t)(rowB0 + (t >> 2)) * DM + (t & 3) * 8;
  bf16* la = lA + w * 512;
  bf16* lb = lB + w * 512;
  const int arow = wr * 64 + c, brow = wc * 64 + c;
  for (int k0 = 0; k0 < DM; k0 += 32) {
    gload16(ga + k0,            la);
    gload16(ga + k0 + 64 * DM,  la + 2048);
    gload16(gb + k0,            lb);
    gload16(gb + k0 + 64 * DM,  lb + 2048);
    __syncthreads();
    bf16x8 af[4], bf_[4];
#pragma unroll
    for (int mi = 0; mi < 4; mi++) af[mi]  = *(const bf16x8*)(lA + (arow + mi * 16) * 32 + g * 8);
#pragma unroll
    for (int ni = 0; ni < 4; ni++) bf_[ni] = *(const bf16x8*)(lB + (brow + ni * 16) * 32 + g * 8);
#pragma unroll
    for (int mi = 0; mi < 4; mi++)
#pragma unroll
      for (int ni = 0; ni < 4; ni++)
        acc[mi][ni] = mfma16(af[mi], bf_[ni], acc[mi][ni]);
    __syncthreads();
  }
}

// ---------------- QKV projection + RoPE epilogue ----------------
__global__ __launch_bounds__(256, 2) void qkv_kernel(const bf16* __restrict__ xb,
    const bf16* __restrict__ wqkv, const fx2* __restrict__ tab,
    bf16* __restrict__ Qb, bf16* __restrict__ Kb, bf16* __restrict__ VTb) {
  f32x4 acc[4][4];
  const int rowA0 = blockIdx.y * 128, rowB0 = blockIdx.x * 128;
  gemm_bt_128(xb, wqkv, rowA0, rowB0, acc);
  const int t = threadIdx.x, w = t >> 6, lane = t & 63;
  const int wr = w >> 1, wc = w & 1, g = lane >> 4, c = lane & 15;
  const int which = rowB0 >> 10;
#pragma unroll
  for (int mi = 0; mi < 4; mi++)
#pragma unroll
    for (int ni = 0; ni < 4; ni++) {
      const int ncol = rowB0 + wc * 64 + ni * 16 + c;
      const int nn = ncol & (DM - 1), h = nn >> 6, dd = nn & 63;
#pragma unroll
      for (int j = 0; j < 4; j++) {
        const int mrow = rowA0 + wr * 64 + mi * 16 + 4 * g + j;
        const int b = mrow >> 11, s = mrow & (SS - 1);
        float v = acc[mi][ni][j];
        if (which < 2) {
          float partner = __shfl_xor(v, 1);
          fx2 cs = tab[s * 32 + (dd >> 1)];
          v = v * cs.x + ((dd & 1) ? partner : -partner) * cs.y;
          bf16* dst = which == 0 ? Qb : Kb;
          dst[((size_t)((b * NH + h) * SS + s)) * HD + dd] = (bf16)v;
        } else {
          VTb[((size_t)((b * NH + h) * HD + dd)) * SS + s] = (bf16)v;
        }
      }
    }
}

// ---------------- flash attention (causal), 1 wave/block, XCD-local, K-prefetch ----------------
// flat = bx + 128*by; xcd = flat&7; flat2 = xcd*512 + flat/8  -> each XCD owns 4 bh
// (K/V working set <= 2MB, fits 4MB per-XCD L2). Within an XCD, ci descends =
// longest-first LPT. K double-buffered one tile ahead (static ping-pong kA/kB).
__global__ __launch_bounds__(64, 4) void attn_kernel(const bf16* __restrict__ Q,
    const bf16* __restrict__ K, const bf16* __restrict__ VT, bf16* __restrict__ AO) {
  __shared__ __align__(16) unsigned char pmem[2048];
  const int flat = blockIdx.x + 128 * blockIdx.y;
  const int flat2 = (flat & 7) * 512 + (flat >> 3);
  const int bh = flat2 >> 7;                 // 0..31
  const int ci = 127 - (flat2 & 127);        // longest first within XCD
  const int lane = threadIdx.x & 63, g = lane >> 4, c = lane & 15;
  const bf16* Qp = Q + (size_t)bh * SS * HD;
  const bf16* Kp = K + (size_t)bh * SS * HD;
  const bf16* Vp = VT + (size_t)bh * HD * SS;
  const int q0r = ci * 16;
  const unsigned lbase = (unsigned)(size_t)(__attribute__((address_space(3))) unsigned char*)&pmem[0];

  // Q fragments (A row = c), pre-scaled by 1/sqrt(64)=0.125
  bf16x8 qa[2];
#pragma unroll
  for (int kc = 0; kc < 2; kc++) {
    bf16x8 xq = *(const bf16x8*)(Qp + (q0r + c) * HD + kc * 32 + g * 8);
#pragma unroll
    for (int e = 0; e < 8; e++) xq[e] = (bf16)((float)xq[e] * 0.125f);
    qa[kc] = xq;
  }

  float m_r[4], l_r[4];
  f32x4 o[4];
#pragma unroll
  for (int j = 0; j < 4; j++) { m_r[j] = -3.0e38f; l_r[j] = 0.f; }
#pragma unroll
  for (int df = 0; df < 4; df++) o[df] = (f32x4){0.f, 0.f, 0.f, 0.f};

  auto loadK = [&](int k0, bf16x8 (&kb)[4][2]) {
#pragma unroll
    for (int kf = 0; kf < 4; kf++) {
      const bf16* kr = Kp + (k0 + kf * 16 + c) * HD + g * 8;
      kb[kf][0] = *(const bf16x8*)(kr);
      kb[kf][1] = *(const bf16x8*)(kr + 32);
    }
  };

  // one full tile: QK -> mask -> online softmax -> LDS tr-relay -> PV
  auto TILE = [&](int k0, bf16x8 (&kb)[4][2]) {
    f32x4 sc[4];
#pragma unroll
    for (int kf = 0; kf < 4; kf++) {
      f32x4 z = (f32x4){0.f, 0.f, 0.f, 0.f};
      z = mfma16(qa[0], kb[kf][0], z);
      z = mfma16(qa[1], kb[kf][1], z);
      sc[kf] = z;
    }
    // V loads (no vmcnt dependency before these; drain under softmax)
    bf16x8 vb[4][2];
#pragma unroll
    for (int df = 0; df < 4; df++) {
      const bf16* vr = Vp + (df * 16 + c) * SS + k0 + g * 8;
      vb[df][0] = *(const bf16x8*)(vr);
      vb[df][1] = *(const bf16x8*)(vr + 32);
    }
    // causal mask (last tile only)
    if (k0 + 63 > q0r) {
#pragma unroll
      for (int kf = 0; kf < 4; kf++) {
        const int kg = k0 + kf * 16 + c;
#pragma unroll
        for (int j = 0; j < 4; j++)
          if (kg > q0r + 4 * g + j) sc[kf][j] = -1.0e30f;
      }
    }
    // online softmax
    float al[4];
#pragma unroll
    for (int j = 0; j < 4; j++) {
      float mx = fmaxf(fmaxf(sc[0][j], sc[1][j]), fmaxf(sc[2][j], sc[3][j]));
      mx = fmaxf(mx, __shfl_xor(mx, 1));
      mx = fmaxf(mx, __shfl_xor(mx, 2));
      mx = fmaxf(mx, __shfl_xor(mx, 4));
      mx = fmaxf(mx, __shfl_xor(mx, 8));
      const float mold = m_r[j];
      const float mnew = fmaxf(mold, mx);
      const float alpha = __builtin_exp2f((mold - mnew) * LOG2E);
      float rs = 0.f;
#pragma unroll
      for (int kf = 0; kf < 4; kf++) {
        float p = __builtin_exp2f((sc[kf][j] - mnew) * LOG2E);
        sc[kf][j] = p; rs += p;
      }
      rs += __shfl_xor(rs, 1);
      rs += __shfl_xor(rs, 2);
      rs += __shfl_xor(rs, 4);
      rs += __shfl_xor(rs, 8);
      l_r[j] = alpha * l_r[j] + rs;
      m_r[j] = mnew;
      al[j] = alpha;
    }
#pragma unroll
    for (int df = 0; df < 4; df++)
#pragma unroll
      for (int j = 0; j < 4; j++) o[df][j] *= al[j];
    // write P^T to LDS: [k][q'] rows of 32B; lane(g,c) -> k=kf*16+c, q'=4g..4g+3
#pragma unroll
    for (int kf = 0; kf < 4; kf++) {
      u32x2 pk;
      pk[0] = pack2(sc[kf][0], sc[kf][1]);
      pk[1] = pack2(sc[kf][2], sc[kf][3]);
      const unsigned a = (unsigned)((kf * 16 + c) * 32 + 8 * g);
      *(u32x2*)(pmem + a) = pk;
    }
    // tr-read P back as PV A-fragments
    asm volatile("s_waitcnt lgkmcnt(0)" ::: "memory");
    bf16x8 pa[2];
#pragma unroll
    for (int kc2 = 0; kc2 < 2; kc2++) {
      const unsigned base = lbase + 128u * (8 * kc2 + 2 * g) + 8 * c;
      u32x2 r0 = tr_read(base);
      u32x2 r1 = tr_read(base + 128);
      pa[kc2] = combine4(r0, r1);
    }
    asm volatile("s_waitcnt lgkmcnt(0)" ::: "memory");
    __builtin_amdgcn_sched_barrier(0);
    // O += P @ V
#pragma unroll
    for (int df = 0; df < 4; df++) {
      o[df] = mfma16(pa[0], vb[df][0], o[df]);
      o[df] = mfma16(pa[1], vb[df][1], o[df]);
    }
  };

  const int nt = q0r / 64 + 1;
  bf16x8 kA[4][2], kB[4][2];
  loadK(0, kA);
  int tv = 0;
  for (; tv + 2 <= nt; tv += 2) {
    loadK((tv + 1) * 64, kB);        // prefetch t+1 (hides under TILE t)
    TILE(tv * 64, kA);
    if (tv + 2 < nt) loadK((tv + 2) * 64, kA);   // prefetch t+2 (hides under TILE t+1)
    TILE((tv + 1) * 64, kB);
  }
  if (tv < nt) TILE(tv * 64, kA);    // odd tail (kA already loaded)

  // ---- epilogue: normalize and store ----
  const int b = bh >> 4, h = bh & 15;
  float inv[4];
#pragma unroll
  for (int j = 0; j < 4; j++) inv[j] = 1.0f / l_r[j];
#pragma unroll
  for (int df = 0; df < 4; df++)
#pragma unroll
    for (int j = 0; j < 4; j++) {
      const int row = b * SS + q0r + 4 * g + j;
      const int col = h * HD + df * 16 + c;
      AO[(size_t)row * DM + col] = (bf16)(o[df][j] * inv[j]);
    }
}

// ---------------- output projection -> fp32 d_out ----------------
__global__ __launch_bounds__(256, 2) void oproj_kernel(const bf16* __restrict__ AO,
    const bf16* __restrict__ wob, float* __restrict__ out) {
  f32x4 acc[4][4];
  const int rowA0 = blockIdx.y * 128, rowB0 = blockIdx.x * 128;
  gemm_bt_128(AO, wob, rowA0, rowB0, acc);
  const int t = threadIdx.x, w = t >> 6, lane = t & 63;
  const int wr = w >> 1, wc = w & 1, g = lane >> 4, c = lane & 15;
#pragma unroll
  for (int mi = 0; mi < 4; mi++)
#pragma unroll
    for (int ni = 0; ni < 4; ni++) {
      const int ncol = rowB0 + wc * 64 + ni * 16 + c;
#pragma unroll
      for (int j = 0; j < 4; j++) {
        const int mrow = rowA0 + wr * 64 + mi * 16 + 4 * g + j;
        out[(size_t)mrow * DM + ncol] = acc[mi][ni][j];
      }
    }
}

extern "C" void kernel_launch(void* const* d_in, const int* in_sizes, int n_in,
                              void* d_out, int out_size, void* d_ws, size_t ws_size,
                              hipStream_t stream) {
  const float* x  = (const float*)d_in[0];
  const float* wq = (const float*)d_in[1];
  const float* wk = (const float*)d_in[2];
  const float* wv = (const float*)d_in[3];
  const float* wo = (const float*)d_in[4];
  const int*   pos = (const int*)d_in[5];
  char* ws = (char*)d_ws;
  bf16* xb   = (bf16*)(ws + OFF_XB);
  bf16* wqkv = (bf16*)(ws + OFF_WQKV);
  bf16* wob  = (bf16*)(ws + OFF_WO);
  fx2*  tab  = (fx2*)(ws + OFF_TAB);
  bf16* Qb   = (bf16*)(ws + OFF_Q);
  bf16* Kb   = (bf16*)(ws + OFF_K);
  bf16* VTb  = (bf16*)(ws + OFF_VT);
  bf16* AOb  = (bf16*)(ws + OFF_AO);

  hipLaunchKernelGGL(prep_kernel, dim3(2048), dim3(256), 0, stream,
                     x, wq, wk, wv, wo, pos, xb, wqkv, wob, tab);
  hipLaunchKernelGGL(qkv_kernel, dim3(24, 32), dim3(256), 0, stream,
                     xb, wqkv, tab, Qb, Kb, VTb);
  hipLaunchKernelGGL(attn_kernel, dim3(128, 32), dim3(64), 0, stream,
                     Qb, Kb, VTb, AOb);
  hipLaunchKernelGGL(oproj_kernel, dim3(8, 32), dim3(256), 0, stream,
                     AOb, wob, (float*)d_out);
}

// Round 7
// 164.577 us; speedup vs baseline: 1.9910x; 1.9910x over previous
//
#include <hip/hip_runtime.h>

typedef __bf16 bf16;
typedef __bf16 bf16x8 __attribute__((ext_vector_type(8)));
typedef __bf16 bf16x4 __attribute__((ext_vector_type(4)));
typedef float f32x4 __attribute__((ext_vector_type(4)));
typedef float fx2 __attribute__((ext_vector_type(2)));
typedef unsigned int u32x2 __attribute__((ext_vector_type(2)));

#define DEV static __device__ __forceinline__

constexpr int BB = 2, SS = 2048, DM = 1024, NH = 16, HD = 64;
constexpr int MTOT = BB * SS;  // 4096
constexpr float LOG2E = 1.4426950408889634f;

// ---- workspace layout (bytes) ----
constexpr size_t OFF_XB   = 0;                                  // bf16 [4096][1024]
constexpr size_t OFF_WQKV = OFF_XB   + (size_t)MTOT * DM * 2;   // bf16 [3072][1024]
constexpr size_t OFF_WO   = OFF_WQKV + (size_t)3 * DM * DM * 2; // bf16 [1024][1024]
constexpr size_t OFF_TAB  = OFF_WO   + (size_t)DM * DM * 2;     // fx2  [2048][32]
constexpr size_t OFF_Q    = OFF_TAB  + (size_t)SS * (HD/2) * 8; // bf16 (B,H,S,d)
constexpr size_t OFF_K    = OFF_Q    + (size_t)MTOT * DM * 2;
constexpr size_t OFF_VT   = OFF_K    + (size_t)MTOT * DM * 2;   // bf16 (B,H,d,S)
constexpr size_t OFF_AO   = OFF_VT   + (size_t)MTOT * DM * 2;   // bf16 [4096][1024]

typedef const __attribute__((address_space(1))) void gas_void;
typedef __attribute__((address_space(3))) void las_void;

DEV void gload16(const bf16* g, bf16* l) {
  __builtin_amdgcn_global_load_lds((gas_void*)g, (las_void*)l, 16, 0, 0);
}

DEV f32x4 mfma16(bf16x8 a, bf16x8 b, f32x4 c) {
  return __builtin_amdgcn_mfma_f32_16x16x32_bf16(a, b, c, 0, 0, 0);
}

DEV unsigned pack2(float a, float b) {
  union { bf16 h[2]; unsigned u; } cv;
  cv.h[0] = (bf16)a; cv.h[1] = (bf16)b;
  return cv.u;
}

DEV u32x2 tr_read(unsigned addr) {
  u32x2 r;
  asm volatile("ds_read_b64_tr_b16 %0, %1" : "=v"(r) : "v"(addr));
  return r;
}

DEV bf16x8 combine4(u32x2 r0, u32x2 r1) {
  union { unsigned u[4]; bf16x8 v; } cv;
  cv.u[0] = r0[0]; cv.u[1] = r0[1]; cv.u[2] = r1[0]; cv.u[3] = r1[1];
  return cv.v;
}

// ---------------- prep: fp32 -> bf16 casts + RoPE table ----------------
__global__ void prep_kernel(const float* __restrict__ x, const float* __restrict__ wq,
    const float* __restrict__ wk, const float* __restrict__ wv, const float* __restrict__ wo,
    const int* __restrict__ pos, bf16* __restrict__ xb, bf16* __restrict__ wqkv,
    bf16* __restrict__ wob, fx2* __restrict__ tab) {
  const int NX4 = MTOT * DM / 4;     // 1048576
  const int NW4 = DM * DM / 4;       // 262144 = 2^18
  const int TOTC = NX4 + 4 * NW4;    // 2097152
  const int NTAB = SS * (HD / 2);    // 65536
  const int total = TOTC + NTAB;
  for (int i = blockIdx.x * blockDim.x + threadIdx.x; i < total; i += gridDim.x * blockDim.x) {
    if (i < TOTC) {
      const float* src; bf16* dst; int off;
      if (i < NX4) { src = x; dst = xb; off = i; }
      else {
        int i2 = i - NX4; int which = i2 >> 18; off = i2 & (NW4 - 1);
        src = which == 0 ? wq : which == 1 ? wk : which == 2 ? wv : wo;
        dst = which == 0 ? wqkv : which == 1 ? wqkv + DM * DM : which == 2 ? wqkv + 2 * DM * DM : wob;
      }
      float4 v = ((const float4*)src)[off];
      bf16x4 o4 = { (bf16)v.x, (bf16)v.y, (bf16)v.z, (bf16)v.w };
      ((bf16x4*)dst)[off] = o4;
    } else {
      int e = i - TOTC;
      int s = e >> 5, p = e & 31;
      float invf = __builtin_exp2f(-(float)p * (13.287712379549449f / 32.0f));
      float ang = (float)pos[s] * invf;
      fx2 cs; cs.x = cosf(ang); cs.y = sinf(ang);
      tab[e] = cs;
    }
  }
}

// ---------------- 128x128 bf16 GEMM mainloop (C[m,n] = sum_k A[m,k]*B[n,k]) ----------------
DEV void gemm_bt_128(const bf16* __restrict__ A, const bf16* __restrict__ Bw,
                     int rowA0, int rowB0, f32x4 (&acc)[4][4]) {
  __shared__ __align__(16) bf16 lA[128 * 32];
  __shared__ __align__(16) bf16 lB[128 * 32];
  const int t = threadIdx.x, w = t >> 6, lane = t & 63;
  const int wr = w >> 1, wc = w & 1, g = lane >> 4, c = lane & 15;
#pragma unroll
  for (int mi = 0; mi < 4; mi++)
#pragma unroll
    for (int ni = 0; ni < 4; ni++) acc[mi][ni] = (f32x4){0.f, 0.f, 0.f, 0.f};
  const bf16* ga = A + (size_t)(rowA0 + (t >> 2)) * DM + (t & 3) * 8;
  const bf16* gb = Bw + (size_t)(rowB0 + (t >> 2)) * DM + (t & 3) * 8;
  bf16* la = lA + w * 512;
  bf16* lb = lB + w * 512;
  const int arow = wr * 64 + c, brow = wc * 64 + c;
  for (int k0 = 0; k0 < DM; k0 += 32) {
    gload16(ga + k0,            la);
    gload16(ga + k0 + 64 * DM,  la + 2048);
    gload16(gb + k0,            lb);
    gload16(gb + k0 + 64 * DM,  lb + 2048);
    __syncthreads();
    bf16x8 af[4], bf_[4];
#pragma unroll
    for (int mi = 0; mi < 4; mi++) af[mi]  = *(const bf16x8*)(lA + (arow + mi * 16) * 32 + g * 8);
#pragma unroll
    for (int ni = 0; ni < 4; ni++) bf_[ni] = *(const bf16x8*)(lB + (brow + ni * 16) * 32 + g * 8);
#pragma unroll
    for (int mi = 0; mi < 4; mi++)
#pragma unroll
      for (int ni = 0; ni < 4; ni++)
        acc[mi][ni] = mfma16(af[mi], bf_[ni], acc[mi][ni]);
    __syncthreads();
  }
}

// ---------------- QKV projection + RoPE epilogue ----------------
__global__ __launch_bounds__(256, 2) void qkv_kernel(const bf16* __restrict__ xb,
    const bf16* __restrict__ wqkv, const fx2* __restrict__ tab,
    bf16* __restrict__ Qb, bf16* __restrict__ Kb, bf16* __restrict__ VTb) {
  f32x4 acc[4][4];
  const int rowA0 = blockIdx.y * 128, rowB0 = blockIdx.x * 128;
  gemm_bt_128(xb, wqkv, rowA0, rowB0, acc);
  const int t = threadIdx.x, w = t >> 6, lane = t & 63;
  const int wr = w >> 1, wc = w & 1, g = lane >> 4, c = lane & 15;
  const int which = rowB0 >> 10;
#pragma unroll
  for (int mi = 0; mi < 4; mi++)
#pragma unroll
    for (int ni = 0; ni < 4; ni++) {
      const int ncol = rowB0 + wc * 64 + ni * 16 + c;
      const int nn = ncol & (DM - 1), h = nn >> 6, dd = nn & 63;
#pragma unroll
      for (int j = 0; j < 4; j++) {
        const int mrow = rowA0 + wr * 64 + mi * 16 + 4 * g + j;
        const int b = mrow >> 11, s = mrow & (SS - 1);
        float v = acc[mi][ni][j];
        if (which < 2) {
          float partner = __shfl_xor(v, 1);
          fx2 cs = tab[s * 32 + (dd >> 1)];
          v = v * cs.x + ((dd & 1) ? partner : -partner) * cs.y;
          bf16* dst = which == 0 ? Qb : Kb;
          dst[((size_t)((b * NH + h) * SS + s)) * HD + dd] = (bf16)v;
        } else {
          VTb[((size_t)((b * NH + h) * HD + dd)) * SS + s] = (bf16)v;
        }
      }
    }
}

// ---------------- flash attention (causal), 1 wave/block, lo/hi paired,
//                  K staged in LDS (double-buffered, swizzled), XCD-local ----------------
// LDS map (bytes): [0,2048) P-relay; [2048,10240) K buf0; [10240,18432) K buf1.
// K tile layout: row-major [64 rows][8 col16 of 16B], with col16 ^= (row&7)
// applied on the GLOBAL source address at stage time and on the ds_read addr
// (rule #21: linear LDS dest + inverse-swizzled source + swizzled read).
__global__ __launch_bounds__(64, 2) void attn_kernel(const bf16* __restrict__ Q,
    const bf16* __restrict__ K, const bf16* __restrict__ VT, bf16* __restrict__ AO) {
  __shared__ __align__(16) unsigned char smem[18432];
  const int flat = blockIdx.x + 64 * blockIdx.y;           // 0..2047
  const int flat2 = (flat & 7) * 256 + (flat >> 3);        // XCD-contiguous
  const int bh = flat2 >> 6;                               // 0..31 (4 per XCD)
  const int pi = flat2 & 63;                               // 0..63
  const int lane = threadIdx.x & 63, g = lane >> 4, c = lane & 15;
  const bf16* Qp = Q + (size_t)bh * SS * HD;
  const bf16* Kp = K + (size_t)bh * SS * HD;
  const bf16* Vp = VT + (size_t)bh * HD * SS;
  const int ql = pi * 16;
  const int qh = 2032 - pi * 16;
  const int kmax_lo = ql + 16;
  const unsigned lbase = (unsigned)(size_t)(__attribute__((address_space(3))) unsigned char*)&smem[0];

  // Q fragments, pre-scaled by 1/sqrt(64)=0.125
  bf16x8 qa_lo[2], qa_hi[2];
#pragma unroll
  for (int kc = 0; kc < 2; kc++) {
    bf16x8 xl = *(const bf16x8*)(Qp + (ql + c) * HD + kc * 32 + g * 8);
    bf16x8 xh = *(const bf16x8*)(Qp + (qh + c) * HD + kc * 32 + g * 8);
#pragma unroll
    for (int e = 0; e < 8; e++) {
      xl[e] = (bf16)((float)xl[e] * 0.125f);
      xh[e] = (bf16)((float)xh[e] * 0.125f);
    }
    qa_lo[kc] = xl; qa_hi[kc] = xh;
  }

  float m_lo[4], l_lo[4], m_hi[4], l_hi[4];
  f32x4 o_lo[4], o_hi[4];
#pragma unroll
  for (int j = 0; j < 4; j++) {
    m_lo[j] = -3.0e38f; l_lo[j] = 0.f; m_hi[j] = -3.0e38f; l_hi[j] = 0.f;
  }
#pragma unroll
  for (int df = 0; df < 4; df++) {
    o_lo[df] = (f32x4){0.f, 0.f, 0.f, 0.f};
    o_hi[df] = (f32x4){0.f, 0.f, 0.f, 0.f};
  }

  // stage one 64x64 K tile into LDS buffer at byte offset koff.
  // lane L: row8 = L>>3, col16' = (L&7) ^ (L>>3)  (inverse swizzle on source)
  const bf16* kSrcBase = Kp + (size_t)(lane >> 3) * HD + ((lane & 7) ^ (lane >> 3)) * 8;
  auto stageK = [&](int k0, unsigned koff) {
    const bf16* src = kSrcBase + (size_t)k0 * HD;
    bf16* dst = (bf16*)(smem + koff);
#pragma unroll
    for (int i = 0; i < 8; i++)
      gload16(src + i * 8 * HD, dst + i * 512);
  };

  // online softmax + P relay for one 16-row chunk
  auto sm_relay = [&](f32x4 (&sc)[4], float (&mr)[4], float (&lr)[4], f32x4 (&oo)[4]) {
    float al[4];
#pragma unroll
    for (int j = 0; j < 4; j++) {
      float mx = fmaxf(fmaxf(sc[0][j], sc[1][j]), fmaxf(sc[2][j], sc[3][j]));
      mx = fmaxf(mx, __shfl_xor(mx, 1));
      mx = fmaxf(mx, __shfl_xor(mx, 2));
      mx = fmaxf(mx, __shfl_xor(mx, 4));
      mx = fmaxf(mx, __shfl_xor(mx, 8));
      const float mold = mr[j];
      const float mnew = fmaxf(mold, mx);
      const float alpha = __builtin_exp2f((mold - mnew) * LOG2E);
      float rs = 0.f;
#pragma unroll
      for (int kf = 0; kf < 4; kf++) {
        float p = __builtin_exp2f((sc[kf][j] - mnew) * LOG2E);
        sc[kf][j] = p; rs += p;
      }
      rs += __shfl_xor(rs, 1);
      rs += __shfl_xor(rs, 2);
      rs += __shfl_xor(rs, 4);
      rs += __shfl_xor(rs, 8);
      lr[j] = alpha * lr[j] + rs;
      mr[j] = mnew;
      al[j] = alpha;
    }
#pragma unroll
    for (int df = 0; df < 4; df++)
#pragma unroll
      for (int j = 0; j < 4; j++) oo[df][j] *= al[j];
#pragma unroll
    for (int kf = 0; kf < 4; kf++) {
      u32x2 pk;
      pk[0] = pack2(sc[kf][0], sc[kf][1]);
      pk[1] = pack2(sc[kf][2], sc[kf][3]);
      const unsigned a = (unsigned)((kf * 16 + c) * 32 + 8 * g);
      *(u32x2*)(smem + a) = pk;
    }
  };

  const int nt = (qh + 79) >> 6;
  stageK(0, 2048);
  unsigned cur = 0;
  for (int tv = 0; tv < nt; ++tv) {
    const int k0 = tv * 64;
    const bool lo_act = (k0 < kmax_lo);
    const unsigned koff = 2048 + cur * 8192;
    // ---- wait K(tv) staged; fence compiler reordering (rule #18/#21) ----
    asm volatile("s_waitcnt vmcnt(0)" ::: "memory");
    __builtin_amdgcn_sched_barrier(0);
    // ---- QK^T from LDS K (swizzled read) ----
    f32x4 sc_hi[4], sc_lo[4];
#pragma unroll
    for (int kf = 0; kf < 4; kf++) {
      const int row = kf * 16 + c;
      const unsigned rb = koff + row * 128;
      bf16x8 kb0 = *(const bf16x8*)(smem + rb + (((unsigned)(g    ) ^ (row & 7)) << 4));
      bf16x8 kb1 = *(const bf16x8*)(smem + rb + (((unsigned)(g + 4) ^ (row & 7)) << 4));
      f32x4 z = (f32x4){0.f, 0.f, 0.f, 0.f};
      z = mfma16(qa_hi[0], kb0, z);
      z = mfma16(qa_hi[1], kb1, z);
      sc_hi[kf] = z;
      if (lo_act) {
        f32x4 y = (f32x4){0.f, 0.f, 0.f, 0.f};
        y = mfma16(qa_lo[0], kb0, y);
        y = mfma16(qa_lo[1], kb1, y);
        sc_lo[kf] = y;
      }
    }
    // ---- prefetch K(tv+1) into the other buffer (latency hides under rest of tile) ----
    if (tv + 1 < nt) stageK(k0 + 64, 2048 + (cur ^ 1) * 8192);
    // ---- V loads (registers; compiler schedules waits before PV) ----
    bf16x8 vb[4][2];
#pragma unroll
    for (int df = 0; df < 4; df++) {
      const bf16* vr = Vp + (df * 16 + c) * SS + k0 + g * 8;
      vb[df][0] = *(const bf16x8*)(vr);
      vb[df][1] = *(const bf16x8*)(vr + 32);
    }
    // ---- causal masks (diagonal tiles only) ----
    if (k0 + 63 > qh) {
#pragma unroll
      for (int kf = 0; kf < 4; kf++) {
        const int kg = k0 + kf * 16 + c;
#pragma unroll
        for (int j = 0; j < 4; j++)
          if (kg > qh + 4 * g + j) sc_hi[kf][j] = -1.0e30f;
      }
    }
    if (lo_act && (k0 + 63 > ql)) {
#pragma unroll
      for (int kf = 0; kf < 4; kf++) {
        const int kg = k0 + kf * 16 + c;
#pragma unroll
        for (int j = 0; j < 4; j++)
          if (kg > ql + 4 * g + j) sc_lo[kf][j] = -1.0e30f;
      }
    }
    // ---- softmax + P relay + PV, hi chunk ----
    sm_relay(sc_hi, m_hi, l_hi, o_hi);
    asm volatile("s_waitcnt lgkmcnt(0)" ::: "memory");
    bf16x8 pa[2];
#pragma unroll
    for (int kc2 = 0; kc2 < 2; kc2++) {
      const unsigned base = lbase + 128u * (8 * kc2 + 2 * g) + 8 * c;
      u32x2 r0 = tr_read(base);
      u32x2 r1 = tr_read(base + 128);
      pa[kc2] = combine4(r0, r1);
    }
    asm volatile("s_waitcnt lgkmcnt(0)" ::: "memory");
    __builtin_amdgcn_sched_barrier(0);
#pragma unroll
    for (int df = 0; df < 4; df++) {
      o_hi[df] = mfma16(pa[0], vb[df][0], o_hi[df]);
      o_hi[df] = mfma16(pa[1], vb[df][1], o_hi[df]);
    }
    // ---- lo chunk (shares staged K and V regs) ----
    if (lo_act) {
      sm_relay(sc_lo, m_lo, l_lo, o_lo);
      asm volatile("s_waitcnt lgkmcnt(0)" ::: "memory");
      bf16x8 pl[2];
#pragma unroll
      for (int kc2 = 0; kc2 < 2; kc2++) {
        const unsigned base = lbase + 128u * (8 * kc2 + 2 * g) + 8 * c;
        u32x2 r0 = tr_read(base);
        u32x2 r1 = tr_read(base + 128);
        pl[kc2] = combine4(r0, r1);
      }
      asm volatile("s_waitcnt lgkmcnt(0)" ::: "memory");
      __builtin_amdgcn_sched_barrier(0);
#pragma unroll
      for (int df = 0; df < 4; df++) {
        o_lo[df] = mfma16(pl[0], vb[df][0], o_lo[df]);
        o_lo[df] = mfma16(pl[1], vb[df][1], o_lo[df]);
      }
    }
    cur ^= 1;
  }
  // ---- epilogue: normalize and store both chunks ----
  const int b = bh >> 4, h = bh & 15;
  auto store_chunk = [&](f32x4 (&oo)[4], float (&lr)[4], int qbase) {
    float inv[4];
#pragma unroll
    for (int j = 0; j < 4; j++) inv[j] = 1.0f / lr[j];
#pragma unroll
    for (int df = 0; df < 4; df++)
#pragma unroll
      for (int j = 0; j < 4; j++) {
        const int row = b * SS + qbase + 4 * g + j;
        const int col = h * HD + df * 16 + c;
        AO[(size_t)row * DM + col] = (bf16)(oo[df][j] * inv[j]);
      }
  };
  store_chunk(o_hi, l_hi, qh);
  store_chunk(o_lo, l_lo, ql);
}

// ---------------- output projection -> fp32 d_out ----------------
__global__ __launch_bounds__(256, 2) void oproj_kernel(const bf16* __restrict__ AO,
    const bf16* __restrict__ wob, float* __restrict__ out) {
  f32x4 acc[4][4];
  const int rowA0 = blockIdx.y * 128, rowB0 = blockIdx.x * 128;
  gemm_bt_128(AO, wob, rowA0, rowB0, acc);
  const int t = threadIdx.x, w = t >> 6, lane = t & 63;
  const int wr = w >> 1, wc = w & 1, g = lane >> 4, c = lane & 15;
#pragma unroll
  for (int mi = 0; mi < 4; mi++)
#pragma unroll
    for (int ni = 0; ni < 4; ni++) {
      const int ncol = rowB0 + wc * 64 + ni * 16 + c;
#pragma unroll
      for (int j = 0; j < 4; j++) {
        const int mrow = rowA0 + wr * 64 + mi * 16 + 4 * g + j;
        out[(size_t)mrow * DM + ncol] = acc[mi][ni][j];
      }
    }
}

extern "C" void kernel_launch(void* const* d_in, const int* in_sizes, int n_in,
                              void* d_out, int out_size, void* d_ws, size_t ws_size,
                              hipStream_t stream) {
  const float* x  = (const float*)d_in[0];
  const float* wq = (const float*)d_in[1];
  const float* wk = (const float*)d_in[2];
  const float* wv = (const float*)d_in[3];
  const float* wo = (const float*)d_in[4];
  const int*   pos = (const int*)d_in[5];
  char* ws = (char*)d_ws;
  bf16* xb   = (bf16*)(ws + OFF_XB);
  bf16* wqkv = (bf16*)(ws + OFF_WQKV);
  bf16* wob  = (bf16*)(ws + OFF_WO);
  fx2*  tab  = (fx2*)(ws + OFF_TAB);
  bf16* Qb   = (bf16*)(ws + OFF_Q);
  bf16* Kb   = (bf16*)(ws + OFF_K);
  bf16* VTb  = (bf16*)(ws + OFF_VT);
  bf16* AOb  = (bf16*)(ws + OFF_AO);

  hipLaunchKernelGGL(prep_kernel, dim3(2048), dim3(256), 0, stream,
                     x, wq, wk, wv, wo, pos, xb, wqkv, wob, tab);
  hipLaunchKernelGGL(qkv_kernel, dim3(24, 32), dim3(256), 0, stream,
                     xb, wqkv, tab, Qb, Kb, VTb);
  hipLaunchKernelGGL(attn_kernel, dim3(64, 32), dim3(64), 0, stream,
                     Qb, Kb, VTb, AOb);
  hipLaunchKernelGGL(oproj_kernel, dim3(8, 32), dim3(256), 0, stream,
                     AOb, wob, (float*)d_out);
}

// Round 8
// 138.192 us; speedup vs baseline: 2.3711x; 1.1909x over previous
//
#include <hip/hip_runtime.h>

typedef __bf16 bf16;
typedef __bf16 bf16x8 __attribute__((ext_vector_type(8)));
typedef __bf16 bf16x4 __attribute__((ext_vector_type(4)));
typedef float f32x4 __attribute__((ext_vector_type(4)));
typedef float f32x16 __attribute__((ext_vector_type(16)));
typedef float fx2 __attribute__((ext_vector_type(2)));

#define DEV static __device__ __forceinline__

constexpr int BB = 2, SS = 2048, DM = 1024, NH = 16, HD = 64;
constexpr int MTOT = BB * SS;  // 4096
constexpr float LOG2E = 1.4426950408889634f;

// ---- workspace layout (bytes) ----
constexpr size_t OFF_XB   = 0;                                  // bf16 [4096][1024]
constexpr size_t OFF_WQKV = OFF_XB   + (size_t)MTOT * DM * 2;   // bf16 [3072][1024]
constexpr size_t OFF_WO   = OFF_WQKV + (size_t)3 * DM * DM * 2; // bf16 [1024][1024]
constexpr size_t OFF_TAB  = OFF_WO   + (size_t)DM * DM * 2;     // fx2  [2048][32]
constexpr size_t OFF_Q    = OFF_TAB  + (size_t)SS * (HD/2) * 8; // bf16 (B,H,S,d)
constexpr size_t OFF_K    = OFF_Q    + (size_t)MTOT * DM * 2;
constexpr size_t OFF_VT   = OFF_K    + (size_t)MTOT * DM * 2;   // bf16 (B,H,d,S)
constexpr size_t OFF_AO   = OFF_VT   + (size_t)MTOT * DM * 2;   // bf16 [4096][1024]

typedef const __attribute__((address_space(1))) void gas_void;
typedef __attribute__((address_space(3))) void las_void;

DEV void gload16(const bf16* g, bf16* l) {
  __builtin_amdgcn_global_load_lds((gas_void*)g, (las_void*)l, 16, 0, 0);
}

DEV f32x4 mfma16(bf16x8 a, bf16x8 b, f32x4 c) {
  return __builtin_amdgcn_mfma_f32_16x16x32_bf16(a, b, c, 0, 0, 0);
}

DEV f32x16 mfma32(bf16x8 a, bf16x8 b, f32x16 c) {
  return __builtin_amdgcn_mfma_f32_32x32x16_bf16(a, b, c, 0, 0, 0);
}

DEV unsigned pack2(float a, float b) {
  union { bf16 h[2]; unsigned u; } cv;
  cv.h[0] = (bf16)a; cv.h[1] = (bf16)b;
  return cv.u;
}

// ---------------- prep: fp32 -> bf16 casts + RoPE table ----------------
__global__ void prep_kernel(const float* __restrict__ x, const float* __restrict__ wq,
    const float* __restrict__ wk, const float* __restrict__ wv, const float* __restrict__ wo,
    const int* __restrict__ pos, bf16* __restrict__ xb, bf16* __restrict__ wqkv,
    bf16* __restrict__ wob, fx2* __restrict__ tab) {
  const int NX4 = MTOT * DM / 4;     // 1048576
  const int NW4 = DM * DM / 4;       // 262144 = 2^18
  const int TOTC = NX4 + 4 * NW4;    // 2097152
  const int NTAB = SS * (HD / 2);    // 65536
  const int total = TOTC + NTAB;
  for (int i = blockIdx.x * blockDim.x + threadIdx.x; i < total; i += gridDim.x * blockDim.x) {
    if (i < TOTC) {
      const float* src; bf16* dst; int off;
      if (i < NX4) { src = x; dst = xb; off = i; }
      else {
        int i2 = i - NX4; int which = i2 >> 18; off = i2 & (NW4 - 1);
        src = which == 0 ? wq : which == 1 ? wk : which == 2 ? wv : wo;
        dst = which == 0 ? wqkv : which == 1 ? wqkv + DM * DM : which == 2 ? wqkv + 2 * DM * DM : wob;
      }
      float4 v = ((const float4*)src)[off];
      bf16x4 o4 = { (bf16)v.x, (bf16)v.y, (bf16)v.z, (bf16)v.w };
      ((bf16x4*)dst)[off] = o4;
    } else {
      int e = i - TOTC;
      int s = e >> 5, p = e & 31;
      float invf = __builtin_exp2f(-(float)p * (13.287712379549449f / 32.0f));
      float ang = (float)pos[s] * invf;
      fx2 cs; cs.x = cosf(ang); cs.y = sinf(ang);
      tab[e] = cs;
    }
  }
}

// ---------------- 128x128 bf16 GEMM mainloop (C[m,n] = sum_k A[m,k]*B[n,k]) ----------------
DEV void gemm_bt_128(const bf16* __restrict__ A, const bf16* __restrict__ Bw,
                     int rowA0, int rowB0, f32x4 (&acc)[4][4]) {
  __shared__ __align__(16) bf16 lA[128 * 32];
  __shared__ __align__(16) bf16 lB[128 * 32];
  const int t = threadIdx.x, w = t >> 6, lane = t & 63;
  const int wr = w >> 1, wc = w & 1, g = lane >> 4, c = lane & 15;
#pragma unroll
  for (int mi = 0; mi < 4; mi++)
#pragma unroll
    for (int ni = 0; ni < 4; ni++) acc[mi][ni] = (f32x4){0.f, 0.f, 0.f, 0.f};
  const bf16* ga = A + (size_t)(rowA0 + (t >> 2)) * DM + (t & 3) * 8;
  const bf16* gb = Bw + (size_t)(rowB0 + (t >> 2)) * DM + (t & 3) * 8;
  bf16* la = lA + w * 512;
  bf16* lb = lB + w * 512;
  const int arow = wr * 64 + c, brow = wc * 64 + c;
  for (int k0 = 0; k0 < DM; k0 += 32) {
    gload16(ga + k0,            la);
    gload16(ga + k0 + 64 * DM,  la + 2048);
    gload16(gb + k0,            lb);
    gload16(gb + k0 + 64 * DM,  lb + 2048);
    __syncthreads();
    bf16x8 af[4], bf_[4];
#pragma unroll
    for (int mi = 0; mi < 4; mi++) af[mi]  = *(const bf16x8*)(lA + (arow + mi * 16) * 32 + g * 8);
#pragma unroll
    for (int ni = 0; ni < 4; ni++) bf_[ni] = *(const bf16x8*)(lB + (brow + ni * 16) * 32 + g * 8);
#pragma unroll
    for (int mi = 0; mi < 4; mi++)
#pragma unroll
      for (int ni = 0; ni < 4; ni++)
        acc[mi][ni] = mfma16(af[mi], bf_[ni], acc[mi][ni]);
    __syncthreads();
  }
}

// ---------------- QKV projection + RoPE epilogue ----------------
__global__ __launch_bounds__(256, 2) void qkv_kernel(const bf16* __restrict__ xb,
    const bf16* __restrict__ wqkv, const fx2* __restrict__ tab,
    bf16* __restrict__ Qb, bf16* __restrict__ Kb, bf16* __restrict__ VTb) {
  f32x4 acc[4][4];
  const int rowA0 = blockIdx.y * 128, rowB0 = blockIdx.x * 128;
  gemm_bt_128(xb, wqkv, rowA0, rowB0, acc);
  const int t = threadIdx.x, w = t >> 6, lane = t & 63;
  const int wr = w >> 1, wc = w & 1, g = lane >> 4, c = lane & 15;
  const int which = rowB0 >> 10;
#pragma unroll
  for (int mi = 0; mi < 4; mi++)
#pragma unroll
    for (int ni = 0; ni < 4; ni++) {
      const int ncol = rowB0 + wc * 64 + ni * 16 + c;
      const int nn = ncol & (DM - 1), h = nn >> 6, dd = nn & 63;
#pragma unroll
      for (int j = 0; j < 4; j++) {
        const int mrow = rowA0 + wr * 64 + mi * 16 + 4 * g + j;
        const int b = mrow >> 11, s = mrow & (SS - 1);
        float v = acc[mi][ni][j];
        if (which < 2) {
          float partner = __shfl_xor(v, 1);
          fx2 cs = tab[s * 32 + (dd >> 1)];
          v = v * cs.x + ((dd & 1) ? partner : -partner) * cs.y;
          bf16* dst = which == 0 ? Qb : Kb;
          dst[((size_t)((b * NH + h) * SS + s)) * HD + dd] = (bf16)v;
        } else {
          VTb[((size_t)((b * NH + h) * HD + dd)) * SS + s] = (bf16)v;
        }
      }
    }
}

// ---------------- flash attention (causal), swapped-operand 32x32 structure ----------------
// 1024 single-wave blocks; XCD-local (4 bh per XCD); each wave runs TWO 32-row
// chunks SEQUENTIALLY (ci=p then ci=63-p -> constant 33 tiles total).
// Swapped QK (A=K,B=Q) and swapped PV (A=V,B=P): C col = lane&31 = q for both,
// so softmax is in-lane (1 cross shuffle) and O-rescale is in-lane.
// K staged in LDS (dbuf 2x8KB, XOR-swizzled source, rule #21). V direct from L2.
// 32x32x16 frags: A/B row = lane&31, k = (lane>>5)*8+e; C col=lane&31,
// row=(reg&3)+8*(reg>>2)+4*(lane>>5)  [guide §3, m74/m101].
__global__ __launch_bounds__(64, 2) void attn_kernel(const bf16* __restrict__ Q,
    const bf16* __restrict__ K, const bf16* __restrict__ VT, bf16* __restrict__ AO) {
  __shared__ __align__(16) unsigned char smem[16384];
  const int flat = blockIdx.x;                       // 0..1023
  const int flat2 = (flat & 7) * 128 + (flat >> 3);  // XCD-contiguous
  const int bh = flat2 >> 5;                         // 0..31 (4 per XCD)
  const int p = flat2 & 31;                          // pair index 0..31
  const int lane = threadIdx.x & 63;
  const int q31 = lane & 31, hi = lane >> 5;
  const bf16* Qp = Q + (size_t)bh * SS * HD;
  const bf16* Kp = K + (size_t)bh * SS * HD;
  const bf16* Vp = VT + (size_t)bh * HD * SS;
  const float SCL = 0.125f * LOG2E;                  // exp2-domain scale

  // stage one 64x64 K tile into LDS at byte offset koff (linear dest,
  // inverse-swizzled source: physical[row][c16] = logical[row][c16^(row&7)])
  const bf16* kSrcBase = Kp + (size_t)(lane >> 3) * HD + ((lane & 7) ^ (lane >> 3)) * 8;
  auto stageK = [&](int k0, unsigned koff) {
    const bf16* src = kSrcBase + (size_t)k0 * HD;
    bf16* dst = (bf16*)(smem + koff);
#pragma unroll
    for (int i = 0; i < 8; i++)
      gload16(src + i * 8 * HD, dst + i * 512);
  };

  auto run_chunk = [&](int qbase, int nt) {
    // Q frags (B-operand): lane: Q[qbase+q31][ds*16 + hi*8 + e], scaled
    bf16x8 qb[4];
#pragma unroll
    for (int ds = 0; ds < 4; ds++) {
      bf16x8 xq = *(const bf16x8*)(Qp + (size_t)(qbase + q31) * HD + ds * 16 + hi * 8);
#pragma unroll
      for (int e = 0; e < 8; e++) xq[e] = (bf16)((float)xq[e] * SCL);
      qb[ds] = xq;
    }
    float m_r = -3.0e38f, lsum = 0.f;
    f32x16 o0, o1;
#pragma unroll
    for (int e = 0; e < 16; e++) { o0[e] = 0.f; o1[e] = 0.f; }

    stageK(0, 0);
    unsigned cur = 0;
    for (int tv = 0; tv < nt; ++tv) {
      const int k0 = tv * 64;
      asm volatile("s_waitcnt vmcnt(0)" ::: "memory");
      __builtin_amdgcn_sched_barrier(0);
      // ---- K frags from LDS (swizzled read), QK^T (swapped: A=K, B=Q) ----
      f32x16 s0, s1;
#pragma unroll
      for (int e = 0; e < 16; e++) { s0[e] = 0.f; s1[e] = 0.f; }
      {
        const unsigned rowb0 = cur * 8192 + q31 * 128;
        const unsigned sw = (unsigned)(q31 & 7) << 4;
#pragma unroll
        for (int ds = 0; ds < 4; ds++) {
          const unsigned co = (((unsigned)(ds * 2 + hi)) << 4) ^ sw;
          bf16x8 kf0 = *(const bf16x8*)(smem + rowb0 + co);
          bf16x8 kf1 = *(const bf16x8*)(smem + rowb0 + 4096 + co);
          s0 = mfma32(kf0, qb[ds], s0);
          s1 = mfma32(kf1, qb[ds], s1);
        }
      }
      // ---- V frags (A-operand for PV), direct from L2; issued BEFORE prefetch
      //      so the pre-PV wait is vmcnt(8), not a drain ----
      bf16x8 vf[2][4];
#pragma unroll
      for (int dt = 0; dt < 2; dt++)
#pragma unroll
        for (int ks = 0; ks < 4; ks++)
          vf[dt][ks] = *(const bf16x8*)(Vp + (size_t)(dt * 32 + q31) * SS + k0 + ks * 16 + hi * 8);
      // ---- prefetch K(tv+1) into other buffer ----
      if (tv + 1 < nt) stageK(k0 + 64, (cur ^ 1) * 8192);
      // ---- causal mask (diagonal tiles only) ----
      if (k0 + 63 > qbase) {
        const int qg = qbase + q31;
#pragma unroll
        for (int r = 0; r < 16; r++) {
          const int kg = k0 + (r & 3) + 8 * (r >> 2) + 4 * hi;
          if (kg > qg)      s0[r] = -1.0e30f;
          if (kg + 32 > qg) s1[r] = -1.0e30f;
        }
      }
      // ---- in-lane online softmax (exp2 domain) ----
      float pm = s0[0];
#pragma unroll
      for (int r = 1; r < 16; r++) pm = fmaxf(pm, s0[r]);
#pragma unroll
      for (int r = 0; r < 16; r++) pm = fmaxf(pm, s1[r]);
      pm = fmaxf(pm, __shfl_xor(pm, 32));
      const float mnew = fmaxf(m_r, pm);
      const float alpha = __builtin_exp2f(m_r - mnew);
      float rs = 0.f;
#pragma unroll
      for (int r = 0; r < 16; r++) {
        s0[r] = __builtin_exp2f(s0[r] - mnew); rs += s0[r];
        s1[r] = __builtin_exp2f(s1[r] - mnew); rs += s1[r];
      }
      rs += __shfl_xor(rs, 32);
      lsum = alpha * lsum + rs;
      m_r = mnew;
#pragma unroll
      for (int e = 0; e < 16; e++) { o0[e] *= alpha; o1[e] *= alpha; }
      // ---- pack P into B-frags (T12 pattern: 16 pack2 + 8 shfl_xor(32)) ----
      // slice ks: kb=ks>>1, rbase=8*(ks&1); in-lane a=k{4hi+0..3}, b=k{8+4hi+0..3}
      bf16x8 pf[4];
#pragma unroll
      for (int ks = 0; ks < 4; ks++) {
        const int rb = 8 * (ks & 1);
        float va0, va1, va2, va3, vb0, vb1, vb2, vb3;
        if (ks < 2) {
          va0 = s0[rb]; va1 = s0[rb + 1]; va2 = s0[rb + 2]; va3 = s0[rb + 3];
          vb0 = s0[rb + 4]; vb1 = s0[rb + 5]; vb2 = s0[rb + 6]; vb3 = s0[rb + 7];
        } else {
          va0 = s1[rb]; va1 = s1[rb + 1]; va2 = s1[rb + 2]; va3 = s1[rb + 3];
          vb0 = s1[rb + 4]; vb1 = s1[rb + 5]; vb2 = s1[rb + 6]; vb3 = s1[rb + 7];
        }
        const unsigned a01 = pack2(va0, va1), a23 = pack2(va2, va3);
        const unsigned b01 = pack2(vb0, vb1), b23 = pack2(vb2, vb3);
        const unsigned z1 = (unsigned)__shfl_xor((int)(hi ? a01 : b01), 32);
        const unsigned z2 = (unsigned)__shfl_xor((int)(hi ? a23 : b23), 32);
        union { unsigned u[4]; bf16x8 v; } cv;
        cv.u[0] = hi ? z1 : a01;
        cv.u[1] = hi ? z2 : a23;
        cv.u[2] = hi ? b01 : z1;
        cv.u[3] = hi ? b23 : z2;
        pf[ks] = cv.v;
      }
      // ---- PV (swapped: A=V, B=P) -> O'[d][q], col=q in-lane ----
#pragma unroll
      for (int ks = 0; ks < 4; ks++) {
        o0 = mfma32(vf[0][ks], pf[ks], o0);
        o1 = mfma32(vf[1][ks], pf[ks], o1);
      }
      cur ^= 1;
    }
    // ---- epilogue: in-lane normalize, store 8B groups ----
    const float inv = 1.0f / lsum;
    const int b = bh >> 4, h = bh & 15;
    const size_t rowb = ((size_t)(b * SS + qbase + q31)) * DM + h * HD;
#pragma unroll
    for (int g2 = 0; g2 < 4; g2++) {
      bf16x4 w0, w1;
#pragma unroll
      for (int j = 0; j < 4; j++) {
        w0[j] = (bf16)(o0[4 * g2 + j] * inv);
        w1[j] = (bf16)(o1[4 * g2 + j] * inv);
      }
      *(bf16x4*)(AO + rowb +      8 * g2 + 4 * hi) = w0;
      *(bf16x4*)(AO + rowb + 32 + 8 * g2 + 4 * hi) = w1;
    }
  };

  run_chunk(p * 32, p / 2 + 1);
  const int ph = 63 - p;
  run_chunk(ph * 32, ph / 2 + 1);
}

// ---------------- output projection -> fp32 d_out ----------------
__global__ __launch_bounds__(256, 2) void oproj_kernel(const bf16* __restrict__ AO,
    const bf16* __restrict__ wob, float* __restrict__ out) {
  f32x4 acc[4][4];
  const int rowA0 = blockIdx.y * 128, rowB0 = blockIdx.x * 128;
  gemm_bt_128(AO, wob, rowA0, rowB0, acc);
  const int t = threadIdx.x, w = t >> 6, lane = t & 63;
  const int wr = w >> 1, wc = w & 1, g = lane >> 4, c = lane & 15;
#pragma unroll
  for (int mi = 0; mi < 4; mi++)
#pragma unroll
    for (int ni = 0; ni < 4; ni++) {
      const int ncol = rowB0 + wc * 64 + ni * 16 + c;
#pragma unroll
      for (int j = 0; j < 4; j++) {
        const int mrow = rowA0 + wr * 64 + mi * 16 + 4 * g + j;
        out[(size_t)mrow * DM + ncol] = acc[mi][ni][j];
      }
    }
}

extern "C" void kernel_launch(void* const* d_in, const int* in_sizes, int n_in,
                              void* d_out, int out_size, void* d_ws, size_t ws_size,
                              hipStream_t stream) {
  const float* x  = (const float*)d_in[0];
  const float* wq = (const float*)d_in[1];
  const float* wk = (const float*)d_in[2];
  const float* wv = (const float*)d_in[3];
  const float* wo = (const float*)d_in[4];
  const int*   pos = (const int*)d_in[5];
  char* ws = (char*)d_ws;
  bf16* xb   = (bf16*)(ws + OFF_XB);
  bf16* wqkv = (bf16*)(ws + OFF_WQKV);
  bf16* wob  = (bf16*)(ws + OFF_WO);
  fx2*  tab  = (fx2*)(ws + OFF_TAB);
  bf16* Qb   = (bf16*)(ws + OFF_Q);
  bf16* Kb   = (bf16*)(ws + OFF_K);
  bf16* VTb  = (bf16*)(ws + OFF_VT);
  bf16* AOb  = (bf16*)(ws + OFF_AO);

  hipLaunchKernelGGL(prep_kernel, dim3(2048), dim3(256), 0, stream,
                     x, wq, wk, wv, wo, pos, xb, wqkv, wob, tab);
  hipLaunchKernelGGL(qkv_kernel, dim3(24, 32), dim3(256), 0, stream,
                     xb, wqkv, tab, Qb, Kb, VTb);
  hipLaunchKernelGGL(attn_kernel, dim3(1024), dim3(64), 0, stream,
                     Qb, Kb, VTb, AOb);
  hipLaunchKernelGGL(oproj_kernel, dim3(8, 32), dim3(256), 0, stream,
                     AOb, wob, (float*)d_out);
}